// Round 11
// baseline (1818.411 us; speedup 1.0000x reference)
//
#include <hip/hip_runtime.h>

typedef _Float16 f16;
typedef unsigned short u16;
typedef unsigned int u32;
typedef _Float16 f16x4 __attribute__((ext_vector_type(4)));
typedef _Float16 f16x8 __attribute__((ext_vector_type(8)));
typedef float    floatx4 __attribute__((ext_vector_type(4)));

#define N_NODES 50000
#define N_EDGES 300000
#define ANNOT   200
#define KXP     224     // x K padded to multiple of 32
#define HID     256

// Device-pass-only intrinsics (undeclared in hipcc's host pass).
__device__ __forceinline__ floatx4 mfma_16x16x32_f16(f16x8 a, f16x8 b, floatx4 c) {
#if defined(__HIP_DEVICE_COMPILE__)
    return __builtin_amdgcn_mfma_f32_16x16x32_f16(a, b, c, 0, 0, 0);
#else
    return c;
#endif
}
__device__ __forceinline__ void gload_lds16(const f16* g, f16* l) {
#if defined(__HIP_DEVICE_COMPILE__)
    __builtin_amdgcn_global_load_lds((const __attribute__((address_space(1))) void*)g,
                                     (__attribute__((address_space(3))) void*)l, 16, 0, 0);
#else
    (void)g; (void)l;
#endif
}

__device__ __forceinline__ float sigm(float x) { return 1.0f / (1.0f + __expf(-x)); }
__device__ __forceinline__ float tanh_fast(float x) { return 1.0f - 2.0f / (1.0f + __expf(2.0f * x)); }

// ---------- dtype helpers ----------
__device__ __forceinline__ float bf_bits_to_f32(u16 u) {
    union { u32 i; float f; } v; v.i = ((u32)u) << 16; return v.f;
}
__device__ __forceinline__ u16 f32_to_bf_bits(float f) {
    union { float f; u32 i; } v; v.f = f;
    u32 b = v.i;
    b += 0x7FFFu + ((b >> 16) & 1u);
    return (u16)(b >> 16);
}
// flag: 0 = inputs are bf16 (u16), 1 = inputs are float32
__device__ __forceinline__ float load_in(const void* p, long i, int flag) {
    if (flag) return ((const float*)p)[i];
    return bf_bits_to_f32(((const u16*)p)[i]);
}

// ---------- dtype probe ----------
__global__ void probe_dtype(const u32* __restrict__ xw, int* __restrict__ flag) {
    __shared__ int cnt;
    if (threadIdx.x == 0) cnt = 0;
    __syncthreads();
    int c = 0;
    for (int i = threadIdx.x; i < 256; i += 64) {
        u32 lo = xw[i] & 0xFFFFu;
        u32 e = (lo >> 7) & 0xFFu;
        if (e >= 105u && e <= 140u) c++;
    }
    atomicAdd(&cnt, c);
    __syncthreads();
    if (threadIdx.x == 0) flag[0] = (cnt > 128) ? 0 : 1;
}

// ---------- prep ----------
__global__ void cvt_f16(const void* __restrict__ in, f16* __restrict__ out, int n,
                        const int* __restrict__ flagp) {
    const int flag = *flagp;
    const int i = blockIdx.x * 256 + threadIdx.x;
    if (i < n) out[i] = (f16)load_in(in, i, flag);
}

// WrT[n][k] (256 x KXP), from W_reduce [256,200] row-major
__global__ void build_wrT(const void* __restrict__ Wre, f16* __restrict__ WrT,
                          const int* __restrict__ flagp) {
    const int flag = *flagp;
    const int i = blockIdx.x * 256 + threadIdx.x;
    if (i >= 256 * KXP) return;
    const int n = i / KXP, k = i - n * KXP;
    WrT[i] = (k < ANNOT) ? (f16)load_in(Wre, (long)n * ANNOT + k, flag) : (f16)0.0f;
}

// Bb8[s][1024][512]; row = chblk*128 + g*32 + c, channel ch = chblk*32+c.
// k<256 half multiplies hsum (uses Wc = Wih_sub @ Wg^T); k>=256 multiplies h (Whh).
// g=0 r, g=1 z, g=2 i_n (Wc only), g=3 h_n (Whh only)
__global__ void build_bb8(const f16* __restrict__ Wc, const void* __restrict__ Whh,
                          f16* __restrict__ Bb, const int* __restrict__ flagp) {
    const int flag = *flagp;
    const int i = blockIdx.x * 256 + threadIdx.x;   // 8 * 1024 * 512
    const int s = i >> 19;
    const int rem = i & 524287;
    const int row = rem >> 9;
    const int k = rem & 511;
    const int chblk = row >> 7;
    const int r = row & 127;
    const int g = r >> 5;
    const int c = r & 31;
    const int ch = chblk * 32 + c;
    f16 v = (f16)0.0f;
    if (g == 0) {
        v = (k < 256) ? Wc[(long)ch * 2048 + s * 256 + k]
                      : (f16)load_in(Whh, (long)ch * 256 + (k - 256), flag);
    } else if (g == 1) {
        v = (k < 256) ? Wc[(long)(256 + ch) * 2048 + s * 256 + k]
                      : (f16)load_in(Whh, (long)(256 + ch) * 256 + (k - 256), flag);
    } else if (g == 2) {
        if (k < 256) v = Wc[(long)(512 + ch) * 2048 + s * 256 + k];
    } else {
        if (k >= 256) v = (f16)load_in(Whh, (long)(512 + ch) * 256 + (k - 256), flag);
    }
    Bb[i] = v;
}

// small fp32 params: brz[512]=b_ih+b_hh, bin[256], bhn[256], br0[256], wlin[512], blin[2]
__global__ void build_small(const void* b_ih, const void* b_hh, const void* b_red,
                            const void* W_lin, const void* b_lin,
                            float* __restrict__ sp, const int* __restrict__ flagp) {
    const int flag = *flagp;
    const int i = blockIdx.x * 256 + threadIdx.x;
    if (i < 512) {
        sp[i] = load_in(b_ih, i, flag) + load_in(b_hh, i, flag);
    } else if (i < 768) {
        sp[i] = load_in(b_ih, 512 + (i - 512), flag);
    } else if (i < 1024) {
        sp[i] = load_in(b_hh, 512 + (i - 768), flag);
    } else if (i < 1280) {
        sp[i] = load_in(b_red, i - 1024, flag);
    } else if (i < 1792) {
        sp[i] = load_in(W_lin, i - 1280, flag);
    } else if (i < 1794) {
        sp[i] = load_in(b_lin, i - 1792, flag);
    }
}

// x_cvt [N, KXP] f16, zero-padded
__global__ void build_xcvt(const void* __restrict__ x, f16* __restrict__ xc,
                           const int* __restrict__ flagp) {
    const int flag = *flagp;
    const long i = (long)blockIdx.x * 256 + threadIdx.x;
    if (i >= (long)N_NODES * KXP) return;
    const long r = i / KXP;
    const int  k = (int)(i - r * KXP);
    xc[i] = (k < ANNOT) ? (f16)load_in(x, r * ANNOT + k, flag) : (f16)0.0f;
}

// ---------- CSR build ----------
__global__ void zero_i32(int* __restrict__ p, int n) {
    const int i = blockIdx.x * 256 + threadIdx.x;
    if (i < n) p[i] = 0;
}
__global__ void hist_kernel(const int* __restrict__ dst, int* __restrict__ deg, int n) {
    const int e = blockIdx.x * 256 + threadIdx.x;
    if (e < n) atomicAdd(&deg[dst[e]], 1);
}
__global__ void block_sum(const int* __restrict__ deg, int* __restrict__ partial, int n) {
    __shared__ int s[256];
    const int i = blockIdx.x * 256 + threadIdx.x;
    s[threadIdx.x] = (i < n) ? deg[i] : 0;
    __syncthreads();
    for (int off = 128; off > 0; off >>= 1) {
        if (threadIdx.x < off) s[threadIdx.x] += s[threadIdx.x + off];
        __syncthreads();
    }
    if (threadIdx.x == 0) partial[blockIdx.x] = s[0];
}
__global__ void scan_partials(int* __restrict__ partial, int nb, int* __restrict__ total_out) {
    __shared__ int s[256];
    const int t = threadIdx.x;
    s[t] = (t < nb) ? partial[t] : 0;
    __syncthreads();
    for (int off = 1; off < 256; off <<= 1) {
        int v = (t >= off) ? s[t - off] : 0;
        __syncthreads();
        s[t] += v;
        __syncthreads();
    }
    if (t < nb) partial[t] = (t == 0) ? 0 : s[t - 1];
    if (t == 0) *total_out = s[255];
}
__global__ void scan_block(const int* __restrict__ deg, const int* __restrict__ partial,
                           int* __restrict__ row_off, int* __restrict__ cursor, int n) {
    __shared__ int s[256];
    const int t = threadIdx.x;
    const int i = blockIdx.x * 256 + t;
    const int v = (i < n) ? deg[i] : 0;
    s[t] = v;
    __syncthreads();
    for (int off = 1; off < 256; off <<= 1) {
        int u = (t >= off) ? s[t - off] : 0;
        __syncthreads();
        s[t] += u;
        __syncthreads();
    }
    if (i < n) {
        const int v0 = partial[blockIdx.x] + s[t] - v;
        row_off[i] = v0;
        cursor[i]  = v0;
    }
}
__global__ void fill_kernel(const int* __restrict__ src, const int* __restrict__ dst,
                            int* __restrict__ cursor, int* __restrict__ csr, int n) {
    const int e = blockIdx.x * 256 + threadIdx.x;
    if (e < n) {
        const int p = atomicAdd(&cursor[dst[e]], 1);
        csr[p] = src[e];
    }
}

// ---------- MFMA GEMM: C[M,N](f16) = A[M,K](f16) * Bt[N,K]^T + bias ----------
// 128x128 tile, 4 waves, BK=32, async global->LDS staging.
__global__ __launch_bounds__(256) void mgemm(
    const f16* __restrict__ A, int lda,
    const f16* __restrict__ Bt, int ldb,
    f16* __restrict__ C, int ldc,
    const float* __restrict__ bias,
    int M, int N, int K)
{
    __shared__ __attribute__((aligned(16))) f16 As[128 * 32];
    __shared__ __attribute__((aligned(16))) f16 Bs[128 * 32];
    const int tid  = threadIdx.x;
    const int lane = tid & 63;
    const int wave = tid >> 6;
    const int bm = blockIdx.x * 128;
    const int bn = blockIdx.y * 128;
    const int wm = (wave >> 1) * 64;
    const int wn = (wave & 1) * 64;
    const int quad = lane >> 4;
    const int l16  = lane & 15;

    floatx4 acc[4][4];
#pragma unroll
    for (int i = 0; i < 4; ++i)
#pragma unroll
        for (int j = 0; j < 4; ++j) acc[i][j] = (floatx4)(0.0f);

    for (int k0 = 0; k0 < K; k0 += 32) {
        __syncthreads();
#pragma unroll
        for (int it = 0; it < 2; ++it) {
            const int ci  = it * 256 + tid;   // 0..511
            const int row = ci >> 2;
            const int cg  = ci & 3;
            int ga = bm + row; if (ga > M - 1) ga = M - 1;
            gload_lds16(A + (long)ga * lda + k0 + cg * 8, As + ci * 8);
            gload_lds16(Bt + (long)(bn + row) * ldb + k0 + cg * 8, Bs + ci * 8);
        }
        __syncthreads();

        f16x8 af[4], bfv[4];
#pragma unroll
        for (int i = 0; i < 4; ++i) {
            af[i]  = *(const f16x8*)(As + (wm + i * 16 + l16) * 32 + quad * 8);
            bfv[i] = *(const f16x8*)(Bs + (wn + i * 16 + l16) * 32 + quad * 8);
        }
#pragma unroll
        for (int i = 0; i < 4; ++i)
#pragma unroll
            for (int j = 0; j < 4; ++j)
                acc[i][j] = mfma_16x16x32_f16(af[i], bfv[j], acc[i][j]);
    }

#pragma unroll
    for (int i = 0; i < 4; ++i) {
        const int r0 = bm + wm + i * 16 + quad * 4;
#pragma unroll
        for (int j = 0; j < 4; ++j) {
            const int col = bn + wn + j * 16 + l16;
            const float bv = bias ? bias[col] : 0.0f;
#pragma unroll
            for (int v = 0; v < 4; ++v) {
                const int r = r0 + v;
                if (r < M) C[(long)r * ldc + col] = (f16)(acc[i][j][v] + bv);
            }
        }
    }
}

// ---------- gates GEMM + fused GRU (barrier-free, direct-register) ----------
// No LDS, no __syncthreads: each wave loads its A/B MFMA fragments directly
// global->VGPR (16B/lane; a wave's load = 16 rows x 64 contiguous bytes).
// The compiler schedules loads against MFMAs with plain vmcnt dependences —
// no barrier drain. Gate-skip: k<256 computes {r,z,i_n}; k>=256 {r,z,h_n}.
// XCD swizzle: blockIdx%8 == rb%8 keeps the 8 cb-blocks of a row-block on one
// XCD so A rows are L2-local across their 16x fragment re-reads.
__global__ __launch_bounds__(256) void gemm_gates(
    const f16* __restrict__ agh, const f16* __restrict__ Bb,
    f16* __restrict__ agh_nxt,
    const float* __restrict__ brz, const float* __restrict__ bin,
    const float* __restrict__ bhn, int M)
{
    const int lin = blockIdx.x;
    const int within = lin & 63;
    const int rb = (lin >> 6) * 8 + (within & 7);   // row block
    const int cb = within >> 3;                     // channel block 0..7
    if (rb * 128 >= M) return;

    const int tid  = threadIdx.x;
    const int lane = tid & 63;
    const int wave = tid >> 6;
    const int bm = rb * 128;
    const int wm  = (wave >> 1) * 64;
    const int chh = (wave & 1) * 16;      // channel half within block
    const int quad = lane >> 4;
    const int l16  = lane & 15;

    const f16* ap[4];
#pragma unroll
    for (int i = 0; i < 4; ++i) {
        int r = bm + wm + i * 16 + l16;
        if (r > M - 1) r = M - 1;
        ap[i] = agh + (long)r * 512 + quad * 8;
    }
    const f16* b0p = Bb + (long)(cb * 128 +      chh + l16) * 512 + quad * 8;  // r
    const f16* b1p = Bb + (long)(cb * 128 + 32 + chh + l16) * 512 + quad * 8;  // z
    const f16* b2p = Bb + (long)(cb * 128 + 64 + chh + l16) * 512 + quad * 8;  // i_n
    const f16* b3p = Bb + (long)(cb * 128 + 96 + chh + l16) * 512 + quad * 8;  // h_n

    floatx4 acc[4][4];
#pragma unroll
    for (int i = 0; i < 4; ++i)
#pragma unroll
        for (int j = 0; j < 4; ++j) acc[i][j] = (floatx4)(0.0f);

    // half 0: k in [0,256) -> gates r,z,i_n
#pragma unroll
    for (int kt = 0; kt < 8; ++kt) {
        const int k = kt * 32;
        const f16x8 b0 = *(const f16x8*)(b0p + k);
        const f16x8 b1 = *(const f16x8*)(b1p + k);
        const f16x8 b2 = *(const f16x8*)(b2p + k);
#pragma unroll
        for (int i = 0; i < 4; ++i) {
            const f16x8 a = *(const f16x8*)(ap[i] + k);
            acc[i][0] = mfma_16x16x32_f16(a, b0, acc[i][0]);
            acc[i][1] = mfma_16x16x32_f16(a, b1, acc[i][1]);
            acc[i][2] = mfma_16x16x32_f16(a, b2, acc[i][2]);
        }
    }
    // half 1: k in [256,512) -> gates r,z,h_n
#pragma unroll
    for (int kt = 8; kt < 16; ++kt) {
        const int k = kt * 32;
        const f16x8 b0 = *(const f16x8*)(b0p + k);
        const f16x8 b1 = *(const f16x8*)(b1p + k);
        const f16x8 b3 = *(const f16x8*)(b3p + k);
#pragma unroll
        for (int i = 0; i < 4; ++i) {
            const f16x8 a = *(const f16x8*)(ap[i] + k);
            acc[i][0] = mfma_16x16x32_f16(a, b0, acc[i][0]);
            acc[i][1] = mfma_16x16x32_f16(a, b1, acc[i][1]);
            acc[i][3] = mfma_16x16x32_f16(a, b3, acc[i][3]);
        }
    }

    // epilogue: lane owns channel ch; acc[i][g][v] = gate g preact at row r0+v
    const int ch = cb * 32 + chh + l16;
    const float b_r  = brz[ch];
    const float b_z  = brz[256 + ch];
    const float b_in = bin[ch];
    const float b_hn = bhn[ch];
#pragma unroll
    for (int i = 0; i < 4; ++i) {
        const int r0 = bm + wm + i * 16 + quad * 4;
#pragma unroll
        for (int v = 0; v < 4; ++v) {
            const int r = r0 + v;
            if (r < M) {
                const float rg = sigm(acc[i][0][v] + b_r);
                const float zg = sigm(acc[i][1][v] + b_z);
                const float nn = tanh_fast(acc[i][2][v] + b_in + rg * (acc[i][3][v] + b_hn));
                const float ho = (float)agh[(long)r * 512 + 256 + ch];   // L2-hot
                agh_nxt[(long)r * 512 + 256 + ch] = (f16)((1.0f - zg) * nn + zg * ho);
            }
        }
    }
}

// ---------- aggregate: agh[v][0:256] = sum_{e: dst=v} agh[src[e]][256:512] ----------
// half-wave (32 lanes x f16x8 = 512B row) per node; 2 independent gather chains
__global__ __launch_bounds__(256) void aggregate(
    f16* __restrict__ agh, const int* __restrict__ row_off, const int* __restrict__ csr)
{
    const int node = blockIdx.x * 8 + (threadIdx.x >> 5);
    const int lane = threadIdx.x & 31;
    if (node >= N_NODES) return;
    const int e0 = row_off[node], e1 = row_off[node + 1];
    float a[8] = {0.0f, 0.0f, 0.0f, 0.0f, 0.0f, 0.0f, 0.0f, 0.0f};
    float b[8] = {0.0f, 0.0f, 0.0f, 0.0f, 0.0f, 0.0f, 0.0f, 0.0f};
    int e = e0;
    for (; e + 2 <= e1; e += 2) {
        const int s0 = csr[e];
        const int s1 = csr[e + 1];
        const f16x8 v0 = *(const f16x8*)(agh + (long)s0 * 512 + 256 + lane * 8);
        const f16x8 v1 = *(const f16x8*)(agh + (long)s1 * 512 + 256 + lane * 8);
#pragma unroll
        for (int u = 0; u < 8; ++u) { a[u] += (float)v0[u]; b[u] += (float)v1[u]; }
    }
    if (e < e1) {
        const int s0 = csr[e];
        const f16x8 v0 = *(const f16x8*)(agh + (long)s0 * 512 + 256 + lane * 8);
#pragma unroll
        for (int u = 0; u < 8; ++u) a[u] += (float)v0[u];
    }
    f16x8 o;
#pragma unroll
    for (int u = 0; u < 8; ++u) o[u] = (f16)(a[u] + b[u]);
    *(f16x8*)(agh + (long)node * 512 + lane * 8) = o;
}

// ---------- final head ----------
__global__ __launch_bounds__(256) void final_kernel(
    const f16* __restrict__ h, const float* __restrict__ wlin,
    const float* __restrict__ blin, void* __restrict__ out,
    const int* __restrict__ flagp)
{
    const int flag = *flagp;
    const int node = blockIdx.x * 4 + (threadIdx.x >> 6);
    const int lane = threadIdx.x & 63;
    if (node >= N_NODES) return;
    const f16* hp = h + (long)node * 512;
    float a0 = 0.0f, a1 = 0.0f;
#pragma unroll
    for (int u = 0; u < 4; ++u) {
        const int c = lane * 4 + u;
        float hv = (float)hp[c];
        hv = hv > 0.0f ? hv : 0.0f;
        a0 += hv * wlin[c];
        a1 += hv * wlin[256 + c];
    }
#pragma unroll
    for (int off = 32; off > 0; off >>= 1) {
        a0 += __shfl_down(a0, off);
        a1 += __shfl_down(a1, off);
    }
    if (lane == 0) {
        a0 += blin[0];
        a1 += blin[1];
        const float mx  = fmaxf(a0, a1);
        const float lse = mx + logf(expf(a0 - mx) + expf(a1 - mx));
        const float o0 = a0 - lse, o1 = a1 - lse;
        if (flag) {
            ((float*)out)[(long)node * 2]     = o0;
            ((float*)out)[(long)node * 2 + 1] = o1;
        } else {
            ((u16*)out)[(long)node * 2]     = f32_to_bf_bits(o0);
            ((u16*)out)[(long)node * 2 + 1] = f32_to_bf_bits(o1);
        }
    }
}

extern "C" void kernel_launch(void* const* d_in, const int* in_sizes, int n_in,
                              void* d_out, int out_size, void* d_ws, size_t ws_size,
                              hipStream_t stream)
{
    (void)in_sizes; (void)n_in; (void)out_size; (void)ws_size;
    const void* x        = d_in[0];
    const int*  ei       = (const int*)d_in[1];
    const void* W_reduce = d_in[3];
    const void* b_reduce = d_in[4];
    const void* W_ggc    = d_in[5];
    const void* W_ih     = d_in[6];
    const void* W_hh     = d_in[7];
    const void* b_ih     = d_in[8];
    const void* b_hh     = d_in[9];
    const void* W_lin    = d_in[10];
    const void* b_lin    = d_in[11];
    const int* src = ei;
    const int* dst = ei + N_EDGES;

    char* w = (char*)d_ws;
    auto carve = [&](size_t bytes) -> char* {
        char* p = w;
        w += (bytes + 255) & ~(size_t)255;
        return p;
    };
    // agh layout: [N][512] f16; cols 0..255 = hsum, 256..511 = h
    f16* agh_a = (f16*)carve((size_t)N_NODES * 512 * 2);
    f16* agh_b = (f16*)carve((size_t)N_NODES * 512 * 2);   // union with x_cvt [N,KXP]
    f16* x_cvt = agh_b;   // dead before agh_b's first write (gates s=0)
    f16*   WrT   = (f16*)carve((size_t)256 * KXP * 2);
    f16*   Wih16 = (f16*)carve((size_t)768 * 256 * 2);
    f16*   Wg16  = (f16*)carve((size_t)2048 * 256 * 2);
    f16*   Wc    = (f16*)carve((size_t)768 * 2048 * 2);
    f16*   Bb8   = (f16*)carve((size_t)8 * 1024 * 512 * 2);
    float* sp    = (float*)carve(2048 * 4);
    int*   flag  = (int*)carve(256);
    int* deg     = (int*)carve((size_t)N_NODES * 4);
    int* row_off = (int*)carve((size_t)(N_NODES + 1) * 4);
    int* cursor  = (int*)carve((size_t)N_NODES * 4);
    int* csr     = (int*)carve((size_t)N_EDGES * 4);
    int* partial = (int*)carve(256 * 4);

    float* brz  = sp;
    float* bin  = sp + 512;
    float* bhn  = sp + 768;
    float* br0  = sp + 1024;
    float* wlin = sp + 1280;
    float* blin = sp + 1792;

    probe_dtype<<<1, 64, 0, stream>>>((const u32*)x, flag);

    cvt_f16<<<(768 * 256 + 255) / 256, 256, 0, stream>>>(W_ih, Wih16, 768 * 256, flag);
    cvt_f16<<<(2048 * 256 + 255) / 256, 256, 0, stream>>>(W_ggc, Wg16, 2048 * 256, flag);
    build_wrT<<<(256 * KXP + 255) / 256, 256, 0, stream>>>(W_reduce, WrT, flag);
    build_small<<<8, 256, 0, stream>>>(b_ih, b_hh, b_reduce, W_lin, b_lin, sp, flag);
    build_xcvt<<<(int)(((long)N_NODES * KXP + 255) / 256), 256, 0, stream>>>(x, x_cvt, flag);

    zero_i32<<<196, 256, 0, stream>>>(deg, N_NODES);
    hist_kernel<<<(N_EDGES + 255) / 256, 256, 0, stream>>>(dst, deg, N_EDGES);
    block_sum<<<196, 256, 0, stream>>>(deg, partial, N_NODES);
    scan_partials<<<1, 256, 0, stream>>>(partial, 196, row_off + N_NODES);
    scan_block<<<196, 256, 0, stream>>>(deg, partial, row_off, cursor, N_NODES);
    fill_kernel<<<(N_EDGES + 255) / 256, 256, 0, stream>>>(src, dst, cursor, csr, N_EDGES);

    // Wc[c][s*256+k] = sum_n Wih[c][n] * Wg_s[k][n]  (one GEMM: M=768, N=2048, K=256)
    mgemm<<<dim3(6, 16), 256, 0, stream>>>(Wih16, 256, Wg16, 256, Wc, 2048,
                                           (const float*)nullptr, 768, 2048, 256);
    build_bb8<<<(8 * 1024 * 512) / 256, 256, 0, stream>>>(Wc, W_hh, Bb8, flag);

    // h0 = x @ W_reduce^T + b_reduce -> agh_a cols 256..511
    mgemm<<<dim3(391, 2), 256, 0, stream>>>(x_cvt, KXP, WrT, KXP, agh_a + 256, 512, br0,
                                            N_NODES, 256, KXP);

    for (int s = 0; s < 8; ++s) {
        f16* cur = (s & 1) ? agh_b : agh_a;
        f16* nxt = (s & 1) ? agh_a : agh_b;
        aggregate<<<6250, 256, 0, stream>>>(cur, row_off, csr);
        gemm_gates<<<49 * 64, 256, 0, stream>>>(cur, Bb8 + (size_t)s * 524288, nxt,
                                                brz, bin, bhn, N_NODES);
    }

    // after s=7, h is in agh_a cols 256..511
    final_kernel<<<12500, 256, 0, stream>>>(agh_a + 256, wlin, blin, d_out, flag);
}

// Round 12
// 1041.906 us; speedup vs baseline: 1.7453x; 1.7453x over previous
//
#include <hip/hip_runtime.h>

typedef _Float16 f16;
typedef unsigned short u16;
typedef unsigned int u32;
typedef _Float16 f16x4 __attribute__((ext_vector_type(4)));
typedef _Float16 f16x8 __attribute__((ext_vector_type(8)));
typedef float    floatx4 __attribute__((ext_vector_type(4)));

#define N_NODES 50000
#define N_EDGES 300000
#define ANNOT   200
#define KXP     224     // x K padded to multiple of 32
#define HID     256

// Device-pass-only intrinsics (undeclared in hipcc's host pass).
__device__ __forceinline__ floatx4 mfma_16x16x32_f16(f16x8 a, f16x8 b, floatx4 c) {
#if defined(__HIP_DEVICE_COMPILE__)
    return __builtin_amdgcn_mfma_f32_16x16x32_f16(a, b, c, 0, 0, 0);
#else
    return c;
#endif
}
__device__ __forceinline__ void gload_lds16(const f16* g, f16* l) {
#if defined(__HIP_DEVICE_COMPILE__)
    __builtin_amdgcn_global_load_lds((const __attribute__((address_space(1))) void*)g,
                                     (__attribute__((address_space(3))) void*)l, 16, 0, 0);
#else
    (void)g; (void)l;
#endif
}

__device__ __forceinline__ float sigm(float x) { return 1.0f / (1.0f + __expf(-x)); }
__device__ __forceinline__ float tanh_fast(float x) { return 1.0f - 2.0f / (1.0f + __expf(2.0f * x)); }

// ---------- dtype helpers ----------
__device__ __forceinline__ float bf_bits_to_f32(u16 u) {
    union { u32 i; float f; } v; v.i = ((u32)u) << 16; return v.f;
}
__device__ __forceinline__ u16 f32_to_bf_bits(float f) {
    union { float f; u32 i; } v; v.f = f;
    u32 b = v.i;
    b += 0x7FFFu + ((b >> 16) & 1u);
    return (u16)(b >> 16);
}
// flag: 0 = inputs are bf16 (u16), 1 = inputs are float32
__device__ __forceinline__ float load_in(const void* p, long i, int flag) {
    if (flag) return ((const float*)p)[i];
    return bf_bits_to_f32(((const u16*)p)[i]);
}

// ---------- dtype probe ----------
__global__ void probe_dtype(const u32* __restrict__ xw, int* __restrict__ flag) {
    __shared__ int cnt;
    if (threadIdx.x == 0) cnt = 0;
    __syncthreads();
    int c = 0;
    for (int i = threadIdx.x; i < 256; i += 64) {
        u32 lo = xw[i] & 0xFFFFu;
        u32 e = (lo >> 7) & 0xFFu;
        if (e >= 105u && e <= 140u) c++;
    }
    atomicAdd(&cnt, c);
    __syncthreads();
    if (threadIdx.x == 0) flag[0] = (cnt > 128) ? 0 : 1;
}

// ---------- merged weight prep (one launch) ----------
// [0,196608)        : Wih16 = f16(W_ih)                         (768*256)
// [196608,720896)   : Wg16  = f16(W_ggc)                        (2048*256)
// [720896,778240)   : WrT[n][k] (256 x KXP) zero-padded         (256*KXP)
// [778240,780288)   : sp = brz|bin|bhn|br0|wlin|blin            (2048)
__global__ void prep_all(const void* __restrict__ W_ih, const void* __restrict__ W_ggc,
                         const void* __restrict__ W_re,
                         const void* __restrict__ b_ih, const void* __restrict__ b_hh,
                         const void* __restrict__ b_red,
                         const void* __restrict__ W_lin, const void* __restrict__ b_lin,
                         f16* __restrict__ Wih16, f16* __restrict__ Wg16,
                         f16* __restrict__ WrT, float* __restrict__ sp,
                         const int* __restrict__ flagp)
{
    const int flag = *flagp;
    const int i = blockIdx.x * 256 + threadIdx.x;
    if (i < 196608) {
        Wih16[i] = (f16)load_in(W_ih, i, flag);
    } else if (i < 720896) {
        const int j = i - 196608;
        Wg16[j] = (f16)load_in(W_ggc, j, flag);
    } else if (i < 778240) {
        const int j = i - 720896;
        const int n = j / KXP, k = j - n * KXP;
        WrT[j] = (k < ANNOT) ? (f16)load_in(W_re, (long)n * ANNOT + k, flag) : (f16)0.0f;
    } else if (i < 780288) {
        const int j = i - 778240;
        if (j < 512) {
            sp[j] = load_in(b_ih, j, flag) + load_in(b_hh, j, flag);
        } else if (j < 768) {
            sp[j] = load_in(b_ih, 512 + (j - 512), flag);
        } else if (j < 1024) {
            sp[j] = load_in(b_hh, 512 + (j - 768), flag);
        } else if (j < 1280) {
            sp[j] = load_in(b_red, j - 1024, flag);
        } else if (j < 1792) {
            sp[j] = load_in(W_lin, j - 1280, flag);
        } else if (j < 1794) {
            sp[j] = load_in(b_lin, j - 1792, flag);
        }
    }
}

// Bb8[s][1024][512]; row = chblk*128 + g*32 + c, channel ch = chblk*32+c.
// k<256 half multiplies hsum (uses Wc = Wih_sub @ Wg^T); k>=256 multiplies h (Whh).
// g=0 r, g=1 z, g=2 i_n (Wc only), g=3 h_n (Whh only)
__global__ void build_bb8(const f16* __restrict__ Wc, const void* __restrict__ Whh,
                          f16* __restrict__ Bb, const int* __restrict__ flagp) {
    const int flag = *flagp;
    const int i = blockIdx.x * 256 + threadIdx.x;   // 8 * 1024 * 512
    const int s = i >> 19;
    const int rem = i & 524287;
    const int row = rem >> 9;
    const int k = rem & 511;
    const int chblk = row >> 7;
    const int r = row & 127;
    const int g = r >> 5;
    const int c = r & 31;
    const int ch = chblk * 32 + c;
    f16 v = (f16)0.0f;
    if (g == 0) {
        v = (k < 256) ? Wc[(long)ch * 2048 + s * 256 + k]
                      : (f16)load_in(Whh, (long)ch * 256 + (k - 256), flag);
    } else if (g == 1) {
        v = (k < 256) ? Wc[(long)(256 + ch) * 2048 + s * 256 + k]
                      : (f16)load_in(Whh, (long)(256 + ch) * 256 + (k - 256), flag);
    } else if (g == 2) {
        if (k < 256) v = Wc[(long)(512 + ch) * 2048 + s * 256 + k];
    } else {
        if (k >= 256) v = (f16)load_in(Whh, (long)(512 + ch) * 256 + (k - 256), flag);
    }
    Bb[i] = v;
}

// x_cvt [N, KXP] f16, zero-padded
__global__ void build_xcvt(const void* __restrict__ x, f16* __restrict__ xc,
                           const int* __restrict__ flagp) {
    const int flag = *flagp;
    const long i = (long)blockIdx.x * 256 + threadIdx.x;
    if (i >= (long)N_NODES * KXP) return;
    const long r = i / KXP;
    const int  k = (int)(i - r * KXP);
    xc[i] = (k < ANNOT) ? (f16)load_in(x, r * ANNOT + k, flag) : (f16)0.0f;
}

// ---------- CSR build ----------
__global__ void zero_i32(int* __restrict__ p, int n) {
    const int i = blockIdx.x * 256 + threadIdx.x;
    if (i < n) p[i] = 0;
}
__global__ void hist_kernel(const int* __restrict__ dst, int* __restrict__ deg, int n) {
    const int e = blockIdx.x * 256 + threadIdx.x;
    if (e < n) atomicAdd(&deg[dst[e]], 1);
}
__global__ void block_sum(const int* __restrict__ deg, int* __restrict__ partial, int n) {
    __shared__ int s[256];
    const int i = blockIdx.x * 256 + threadIdx.x;
    s[threadIdx.x] = (i < n) ? deg[i] : 0;
    __syncthreads();
    for (int off = 128; off > 0; off >>= 1) {
        if (threadIdx.x < off) s[threadIdx.x] += s[threadIdx.x + off];
        __syncthreads();
    }
    if (threadIdx.x == 0) partial[blockIdx.x] = s[0];
}
__global__ void scan_partials(int* __restrict__ partial, int nb, int* __restrict__ total_out) {
    __shared__ int s[256];
    const int t = threadIdx.x;
    s[t] = (t < nb) ? partial[t] : 0;
    __syncthreads();
    for (int off = 1; off < 256; off <<= 1) {
        int v = (t >= off) ? s[t - off] : 0;
        __syncthreads();
        s[t] += v;
        __syncthreads();
    }
    if (t < nb) partial[t] = (t == 0) ? 0 : s[t - 1];
    if (t == 0) *total_out = s[255];
}
__global__ void scan_block(const int* __restrict__ deg, const int* __restrict__ partial,
                           int* __restrict__ row_off, int* __restrict__ cursor, int n) {
    __shared__ int s[256];
    const int t = threadIdx.x;
    const int i = blockIdx.x * 256 + t;
    const int v = (i < n) ? deg[i] : 0;
    s[t] = v;
    __syncthreads();
    for (int off = 1; off < 256; off <<= 1) {
        int u = (t >= off) ? s[t - off] : 0;
        __syncthreads();
        s[t] += u;
        __syncthreads();
    }
    if (i < n) {
        const int v0 = partial[blockIdx.x] + s[t] - v;
        row_off[i] = v0;
        cursor[i]  = v0;
    }
}
__global__ void fill_kernel(const int* __restrict__ src, const int* __restrict__ dst,
                            int* __restrict__ cursor, int* __restrict__ csr, int n) {
    const int e = blockIdx.x * 256 + threadIdx.x;
    if (e < n) {
        const int p = atomicAdd(&cursor[dst[e]], 1);
        csr[p] = src[e];
    }
}

// ---------- MFMA GEMM: C[M,N](f16) = A[M,K](f16) * Bt[N,K]^T + bias ----------
// 128x128 tile, 4 waves, BK=32, async global->LDS staging.
__global__ __launch_bounds__(256) void mgemm(
    const f16* __restrict__ A, int lda,
    const f16* __restrict__ Bt, int ldb,
    f16* __restrict__ C, int ldc,
    const float* __restrict__ bias,
    int M, int N, int K)
{
    __shared__ __attribute__((aligned(16))) f16 As[128 * 32];
    __shared__ __attribute__((aligned(16))) f16 Bs[128 * 32];
    const int tid  = threadIdx.x;
    const int lane = tid & 63;
    const int wave = tid >> 6;
    const int bm = blockIdx.x * 128;
    const int bn = blockIdx.y * 128;
    const int wm = (wave >> 1) * 64;
    const int wn = (wave & 1) * 64;
    const int quad = lane >> 4;
    const int l16  = lane & 15;

    floatx4 acc[4][4];
#pragma unroll
    for (int i = 0; i < 4; ++i)
#pragma unroll
        for (int j = 0; j < 4; ++j) acc[i][j] = (floatx4)(0.0f);

    for (int k0 = 0; k0 < K; k0 += 32) {
        __syncthreads();
#pragma unroll
        for (int it = 0; it < 2; ++it) {
            const int ci  = it * 256 + tid;   // 0..511
            const int row = ci >> 2;
            const int cg  = ci & 3;
            int ga = bm + row; if (ga > M - 1) ga = M - 1;
            gload_lds16(A + (long)ga * lda + k0 + cg * 8, As + ci * 8);
            gload_lds16(Bt + (long)(bn + row) * ldb + k0 + cg * 8, Bs + ci * 8);
        }
        __syncthreads();

        f16x8 af[4], bfv[4];
#pragma unroll
        for (int i = 0; i < 4; ++i) {
            af[i]  = *(const f16x8*)(As + (wm + i * 16 + l16) * 32 + quad * 8);
            bfv[i] = *(const f16x8*)(Bs + (wn + i * 16 + l16) * 32 + quad * 8);
        }
#pragma unroll
        for (int i = 0; i < 4; ++i)
#pragma unroll
            for (int j = 0; j < 4; ++j)
                acc[i][j] = mfma_16x16x32_f16(af[i], bfv[j], acc[i][j]);
    }

#pragma unroll
    for (int i = 0; i < 4; ++i) {
        const int r0 = bm + wm + i * 16 + quad * 4;
#pragma unroll
        for (int j = 0; j < 4; ++j) {
            const int col = bn + wn + j * 16 + l16;
            const float bv = bias ? bias[col] : 0.0f;
#pragma unroll
            for (int v = 0; v < 4; ++v) {
                const int r = r0 + v;
                if (r < M) C[(long)r * ldc + col] = (f16)(acc[i][j][v] + bv);
            }
        }
    }
}

// ---------- gates GEMM + fused GRU (round-10 structure: best measured) ----------
// Single chblk/block (92 VGPR, 28 KB LDS, ~5 blocks/CU). 96-row Bs: only the 3
// non-zero gate row-groups staged (g=2 slot holds Bb group 2 (i_n) for k<256,
// group 3 (h_n) for k>=256). BK=64 with XOR bank-swizzle (chunk c of row r at
// slot c^(r&7); staging reads the permuted global chunk so the global_load_lds
// dest stays linear-in-lane). XCD swizzle: blockIdx%8 == rb%8 for L2 locality.
// NOTE (R11 lesson): direct-register fragment loads scatter each wave access
// across 16 cache lines -> TA-bound (8% MfmaUtil). LDS staging IS the coalescer.

#define GATES_STAGE(K0, GHI)                                                        \
    {                                                                               \
        __syncthreads();                                                            \
        _Pragma("unroll")                                                           \
        for (int it_ = 0; it_ < 4; ++it_) {                                         \
            const int ci_  = it_ * 256 + tid;                                       \
            const int row_ = ci_ >> 3;                                              \
            const int lc_  = (ci_ & 7) ^ (row_ & 7);                                \
            int ga_ = bm + row_; if (ga_ > M - 1) ga_ = M - 1;                      \
            gload_lds16(agh + (long)ga_ * 512 + (K0) + lc_ * 8, As + ci_ * 8);      \
        }                                                                           \
        _Pragma("unroll")                                                           \
        for (int it_ = 0; it_ < 3; ++it_) {                                         \
            const int ci_  = it_ * 256 + tid;                                       \
            const int lr_  = ci_ >> 3;                                              \
            const int lc_  = (ci_ & 7) ^ (lr_ & 7);                                 \
            const int g_   = lr_ >> 5;                                              \
            const int c_   = lr_ & 31;                                              \
            const int gm_  = (g_ == 2 && (GHI)) ? 3 : g_;                           \
            gload_lds16(Bb + (long)(cb * 128 + gm_ * 32 + c_) * 512 + (K0) + lc_ * 8, \
                        Bs + ci_ * 8);                                              \
        }                                                                           \
        __syncthreads();                                                            \
    }

#define GATES_STEP(KC, JJ)                                                          \
    {                                                                               \
        const int sl_ = (((KC) >> 3) + quad) ^ xr;                                  \
        f16x8 af_[4];                                                               \
        _Pragma("unroll")                                                           \
        for (int i_ = 0; i_ < 4; ++i_)                                              \
            af_[i_] = *(const f16x8*)(As + (wm + i_ * 16 + l16) * 64 + sl_ * 8);    \
        const f16x8 b0_ = *(const f16x8*)(Bs + (chh + l16) * 64 + sl_ * 8);         \
        const f16x8 b1_ = *(const f16x8*)(Bs + (32 + chh + l16) * 64 + sl_ * 8);    \
        const f16x8 b2_ = *(const f16x8*)(Bs + (64 + chh + l16) * 64 + sl_ * 8);    \
        _Pragma("unroll")                                                           \
        for (int i_ = 0; i_ < 4; ++i_) {                                            \
            acc[i_][0]    = mfma_16x16x32_f16(af_[i_], b0_, acc[i_][0]);            \
            acc[i_][1]    = mfma_16x16x32_f16(af_[i_], b1_, acc[i_][1]);            \
            acc[i_][(JJ)] = mfma_16x16x32_f16(af_[i_], b2_, acc[i_][(JJ)]);         \
        }                                                                           \
    }

__global__ __launch_bounds__(256) void gemm_gates(
    const f16* __restrict__ agh, const f16* __restrict__ Bb,
    f16* __restrict__ agh_nxt,
    const float* __restrict__ brz, const float* __restrict__ bin,
    const float* __restrict__ bhn, int M)
{
    const int lin = blockIdx.x;
    const int within = lin & 63;
    const int rb = (lin >> 6) * 8 + (within & 7);   // row block
    const int cb = within >> 3;                     // channel block 0..7
    if (rb * 128 >= M) return;

    __shared__ __attribute__((aligned(16))) f16 As[128 * 64];
    __shared__ __attribute__((aligned(16))) f16 Bs[96 * 64];
    const int tid  = threadIdx.x;
    const int lane = tid & 63;
    const int wave = tid >> 6;
    const int bm = rb * 128;
    const int wm  = (wave >> 1) * 64;
    const int chh = (wave & 1) * 16;      // channel half within block
    const int quad = lane >> 4;
    const int l16  = lane & 15;
    const int xr   = l16 & 7;
    const int kcap0 = 256 + ((cb * 32) & ~63);  // K-iter holding this block's h cols
    const int koff  = (cb & 1) * 32;            // column offset within that tile

    floatx4 acc[4][4];
#pragma unroll
    for (int i = 0; i < 4; ++i)
#pragma unroll
        for (int j = 0; j < 4; ++j) acc[i][j] = (floatx4)(0.0f);
    f16 h_frag[4][4] = {};

    // half 0: k in [0,256) -> gates r,z,i_n
    for (int k0 = 0; k0 < 256; k0 += 64) {
        GATES_STAGE(k0, 0)
        GATES_STEP(0, 2)
        GATES_STEP(32, 2)
    }
    // half 1: k in [256,512) -> gates r,z,h_n (+ capture h fragment from LDS)
    for (int k0 = 256; k0 < 512; k0 += 64) {
        GATES_STAGE(k0, 1)
        if (k0 == kcap0) {
#pragma unroll
            for (int i = 0; i < 4; ++i)
#pragma unroll
                for (int v = 0; v < 4; ++v) {
                    const int r = wm + i * 16 + quad * 4 + v;
                    const int kcol = koff + chh + l16;
                    const int slot = (kcol >> 3) ^ (r & 7);
                    h_frag[i][v] = As[r * 64 + slot * 8 + (kcol & 7)];
                }
        }
        GATES_STEP(0, 3)
        GATES_STEP(32, 3)
    }

    // epilogue: lane owns channel ch; acc[i][g][v] = gate g preact at row r0+v
    const int ch = cb * 32 + chh + l16;
    const float b_r  = brz[ch];
    const float b_z  = brz[256 + ch];
    const float b_in = bin[ch];
    const float b_hn = bhn[ch];
#pragma unroll
    for (int i = 0; i < 4; ++i) {
        const int r0 = bm + wm + i * 16 + quad * 4;
#pragma unroll
        for (int v = 0; v < 4; ++v) {
            const int r = r0 + v;
            if (r < M) {
                const float rg = sigm(acc[i][0][v] + b_r);
                const float zg = sigm(acc[i][1][v] + b_z);
                const float nn = tanh_fast(acc[i][2][v] + b_in + rg * (acc[i][3][v] + b_hn));
                const float ho = (float)h_frag[i][v];
                agh_nxt[(long)r * 512 + 256 + ch] = (f16)((1.0f - zg) * nn + zg * ho);
            }
        }
    }
}

// ---------- aggregate: agh[v][0:256] = sum_{e: dst=v} agh[src[e]][256:512] ----------
// half-wave (32 lanes x f16x8 = 512B row) per node; 2 independent gather chains
__global__ __launch_bounds__(256) void aggregate(
    f16* __restrict__ agh, const int* __restrict__ row_off, const int* __restrict__ csr)
{
    const int node = blockIdx.x * 8 + (threadIdx.x >> 5);
    const int lane = threadIdx.x & 31;
    if (node >= N_NODES) return;
    const int e0 = row_off[node], e1 = row_off[node + 1];
    float a[8] = {0.0f, 0.0f, 0.0f, 0.0f, 0.0f, 0.0f, 0.0f, 0.0f};
    float b[8] = {0.0f, 0.0f, 0.0f, 0.0f, 0.0f, 0.0f, 0.0f, 0.0f};
    int e = e0;
    for (; e + 2 <= e1; e += 2) {
        const int s0 = csr[e];
        const int s1 = csr[e + 1];
        const f16x8 v0 = *(const f16x8*)(agh + (long)s0 * 512 + 256 + lane * 8);
        const f16x8 v1 = *(const f16x8*)(agh + (long)s1 * 512 + 256 + lane * 8);
#pragma unroll
        for (int u = 0; u < 8; ++u) { a[u] += (float)v0[u]; b[u] += (float)v1[u]; }
    }
    if (e < e1) {
        const int s0 = csr[e];
        const f16x8 v0 = *(const f16x8*)(agh + (long)s0 * 512 + 256 + lane * 8);
#pragma unroll
        for (int u = 0; u < 8; ++u) a[u] += (float)v0[u];
    }
    f16x8 o;
#pragma unroll
    for (int u = 0; u < 8; ++u) o[u] = (f16)(a[u] + b[u]);
    *(f16x8*)(agh + (long)node * 512 + lane * 8) = o;
}

// ---------- final head ----------
__global__ __launch_bounds__(256) void final_kernel(
    const f16* __restrict__ h, const float* __restrict__ wlin,
    const float* __restrict__ blin, void* __restrict__ out,
    const int* __restrict__ flagp)
{
    const int flag = *flagp;
    const int node = blockIdx.x * 4 + (threadIdx.x >> 6);
    const int lane = threadIdx.x & 63;
    if (node >= N_NODES) return;
    const f16* hp = h + (long)node * 512;
    float a0 = 0.0f, a1 = 0.0f;
#pragma unroll
    for (int u = 0; u < 4; ++u) {
        const int c = lane * 4 + u;
        float hv = (float)hp[c];
        hv = hv > 0.0f ? hv : 0.0f;
        a0 += hv * wlin[c];
        a1 += hv * wlin[256 + c];
    }
#pragma unroll
    for (int off = 32; off > 0; off >>= 1) {
        a0 += __shfl_down(a0, off);
        a1 += __shfl_down(a1, off);
    }
    if (lane == 0) {
        a0 += blin[0];
        a1 += blin[1];
        const float mx  = fmaxf(a0, a1);
        const float lse = mx + logf(expf(a0 - mx) + expf(a1 - mx));
        const float o0 = a0 - lse, o1 = a1 - lse;
        if (flag) {
            ((float*)out)[(long)node * 2]     = o0;
            ((float*)out)[(long)node * 2 + 1] = o1;
        } else {
            ((u16*)out)[(long)node * 2]     = f32_to_bf_bits(o0);
            ((u16*)out)[(long)node * 2 + 1] = f32_to_bf_bits(o1);
        }
    }
}

extern "C" void kernel_launch(void* const* d_in, const int* in_sizes, int n_in,
                              void* d_out, int out_size, void* d_ws, size_t ws_size,
                              hipStream_t stream)
{
    (void)in_sizes; (void)n_in; (void)out_size; (void)ws_size;
    const void* x        = d_in[0];
    const int*  ei       = (const int*)d_in[1];
    const void* W_reduce = d_in[3];
    const void* b_reduce = d_in[4];
    const void* W_ggc    = d_in[5];
    const void* W_ih     = d_in[6];
    const void* W_hh     = d_in[7];
    const void* b_ih     = d_in[8];
    const void* b_hh     = d_in[9];
    const void* W_lin    = d_in[10];
    const void* b_lin    = d_in[11];
    const int* src = ei;
    const int* dst = ei + N_EDGES;

    char* w = (char*)d_ws;
    auto carve = [&](size_t bytes) -> char* {
        char* p = w;
        w += (bytes + 255) & ~(size_t)255;
        return p;
    };
    // agh layout: [N][512] f16; cols 0..255 = hsum, 256..511 = h
    f16* agh_a = (f16*)carve((size_t)N_NODES * 512 * 2);
    f16* agh_b = (f16*)carve((size_t)N_NODES * 512 * 2);   // union with x_cvt [N,KXP]
    f16* x_cvt = agh_b;   // dead before agh_b's first write (gates s=0)
    f16*   WrT   = (f16*)carve((size_t)256 * KXP * 2);
    f16*   Wih16 = (f16*)carve((size_t)768 * 256 * 2);
    f16*   Wg16  = (f16*)carve((size_t)2048 * 256 * 2);
    f16*   Wc    = (f16*)carve((size_t)768 * 2048 * 2);
    f16*   Bb8   = (f16*)carve((size_t)8 * 1024 * 512 * 2);
    float* sp    = (float*)carve(2048 * 4);
    int*   flag  = (int*)carve(256);
    int* deg     = (int*)carve((size_t)N_NODES * 4);
    int* row_off = (int*)carve((size_t)(N_NODES + 1) * 4);
    int* cursor  = (int*)carve((size_t)N_NODES * 4);
    int* csr     = (int*)carve((size_t)N_EDGES * 4);
    int* partial = (int*)carve(256 * 4);

    float* brz  = sp;
    float* bin  = sp + 512;
    float* bhn  = sp + 768;
    float* br0  = sp + 1024;
    float* wlin = sp + 1280;
    float* blin = sp + 1792;

    probe_dtype<<<1, 64, 0, stream>>>((const u32*)x, flag);

    prep_all<<<3048, 256, 0, stream>>>(W_ih, W_ggc, W_reduce, b_ih, b_hh, b_reduce,
                                       W_lin, b_lin, Wih16, Wg16, WrT, sp, flag);
    build_xcvt<<<(int)(((long)N_NODES * KXP + 255) / 256), 256, 0, stream>>>(x, x_cvt, flag);

    zero_i32<<<196, 256, 0, stream>>>(deg, N_NODES);
    hist_kernel<<<(N_EDGES + 255) / 256, 256, 0, stream>>>(dst, deg, N_EDGES);
    block_sum<<<196, 256, 0, stream>>>(deg, partial, N_NODES);
    scan_partials<<<1, 256, 0, stream>>>(partial, 196, row_off + N_NODES);
    scan_block<<<196, 256, 0, stream>>>(deg, partial, row_off, cursor, N_NODES);
    fill_kernel<<<(N_EDGES + 255) / 256, 256, 0, stream>>>(src, dst, cursor, csr, N_EDGES);

    // Wc[c][s*256+k] = sum_n Wih[c][n] * Wg_s[k][n]  (one GEMM: M=768, N=2048, K=256)
    mgemm<<<dim3(6, 16), 256, 0, stream>>>(Wih16, 256, Wg16, 256, Wc, 2048,
                                           (const float*)nullptr, 768, 2048, 256);
    build_bb8<<<(8 * 1024 * 512) / 256, 256, 0, stream>>>(Wc, W_hh, Bb8, flag);

    // h0 = x @ W_reduce^T + b_reduce -> agh_a cols 256..511
    mgemm<<<dim3(391, 2), 256, 0, stream>>>(x_cvt, KXP, WrT, KXP, agh_a + 256, 512, br0,
                                            N_NODES, 256, KXP);

    for (int s = 0; s < 8; ++s) {
        f16* cur = (s & 1) ? agh_b : agh_a;
        f16* nxt = (s & 1) ? agh_a : agh_b;
        aggregate<<<6250, 256, 0, stream>>>(cur, row_off, csr);
        gemm_gates<<<49 * 64, 256, 0, stream>>>(cur, Bb8 + (size_t)s * 524288, nxt,
                                                brz, bin, bhn, N_NODES);
    }

    // after s=7, h is in agh_a cols 256..511
    final_kernel<<<12500, 256, 0, stream>>>(agh_a + 256, wlin, blin, d_out, flag);
}